// Round 15
// baseline (57.184 us; speedup 1.0000x reference)
//
#include <hip/hip_runtime.h>
#include <hip/hip_bf16.h>

#define B_ 8
#define N_ 16384
#define S_ 1024
#define K_ 32
#define CSTEM 64
#define CPATCH 128
#define INDIM 91
#define LDH 136     // Hs row stride (bf16): 272B -> 2-way (free)

typedef __attribute__((ext_vector_type(8))) short short8v;  // 8 bf16 = 4 VGPRs
typedef __attribute__((ext_vector_type(4))) float f32x4;

static __device__ __forceinline__ unsigned short f2bf(float f) {
  union { float f; unsigned int u; } v; v.f = f;
  return (unsigned short)((v.u + 0x7FFFu + ((v.u >> 16) & 1u)) >> 16);  // RNE
}

static __device__ __forceinline__ short8v cvt8(const float4 a, const float4 b) {
  unsigned short v[8];
  v[0] = f2bf(a.x); v[1] = f2bf(a.y); v[2] = f2bf(a.z); v[3] = f2bf(a.w);
  v[4] = f2bf(b.x); v[5] = f2bf(b.y); v[6] = f2bf(b.z); v[7] = f2bf(b.w);
  return *(const short8v*)v;
}

// PE/rel fragment: cols [64+kq, 64+kq+8) of one row (verified R8-R14).
static __device__ __forceinline__ short8v pe_frag(
    float r0, float r1, float r2, int kq)
{
  unsigned short v[8];
  #pragma unroll
  for (int j = 0; j < 8; ++j) {
    const int c = 64 + kq + j;
    float val;
    if (c < 67) {
      val = (c == 64) ? r0 : ((c == 65) ? r1 : r2);
    } else if (c < 91) {
      const int qq = c - 67, d = qq >> 3, rbit = qq & 7, band = rbit & 3;
      const float rel = (d == 0) ? r0 : ((d == 1) ? r1 : r2);
      const float ang = rel * ((float)(1 << band) * 3.14159265358979323846f);
      val = (rbit < 4) ? __sinf(ang) : __cosf(ang);
    } else {
      val = 0.f;
    }
    v[j] = f2bf(val);
  }
  return *(const short8v*)v;
}

// -------- Kernel 0: pack w1/w2 into MFMA B-fragment order (bf16) --------
__global__ __launch_bounds__(256) void pack_weights(
    const float* __restrict__ w1, const float* __restrict__ w2,
    unsigned short* __restrict__ w1p, unsigned short* __restrict__ w2p)
{
  const int id = blockIdx.x * 256 + threadIdx.x;
  if (id < 3 * 8 * 64) {                       // w1: K padded 91->96 (3 ksteps)
    const int l = id & 63, ct = (id >> 6) & 7, ks = id >> 9;
    const int col = 16 * ct + (l & 15);
    const int kb = 32 * ks + (l >> 4) * 8;
    unsigned short v[8];
    #pragma unroll
    for (int j = 0; j < 8; ++j) {
      const int k = kb + j;
      v[j] = (k < INDIM) ? f2bf(w1[k * CPATCH + col]) : (unsigned short)0;
    }
    *(short8v*)&w1p[(size_t)id * 8] = *(const short8v*)v;
  } else if (id < 3 * 8 * 64 + 4 * 8 * 64) {   // w2: 4 ksteps
    const int id2 = id - 3 * 8 * 64;
    const int l = id2 & 63, ct = (id2 >> 6) & 7, ks = id2 >> 9;
    const int col = 16 * ct + (l & 15);
    const int kb = 32 * ks + (l >> 4) * 8;
    unsigned short v[8];
    #pragma unroll
    for (int j = 0; j < 8; ++j) v[j] = f2bf(w2[(kb + j) * CPATCH + col]);
    *(short8v*)&w2p[(size_t)id2 * 8] = *(const short8v*)v;
  }
}

// test 4 consecutive points packed in 3 float4 against center (CX,CY,CZ);
// f32 fast path + f64 recheck band (verified R7-R14, decision-identical).
#define TEST4C(V0, V1, V2, CX, CY, CZ, MASKVAR) do {                       \
    MASKVAR = 0u;                                                          \
    const float X[4] = {(V0).x, (V0).w, (V1).z, (V2).y};                   \
    const float Y[4] = {(V0).y, (V1).x, (V1).w, (V2).z};                   \
    const float Z[4] = {(V0).z, (V1).y, (V2).x, (V2).w};                   \
    _Pragma("unroll")                                                      \
    for (int p = 0; p < 4; ++p) {                                          \
      const float dxf = X[p] - (CX), dyf = Y[p] - (CY), dzf = Z[p] - (CZ); \
      const float d2f = fmaf(dxf, dxf, fmaf(dyf, dyf, dzf * dzf));         \
      bool in;                                                             \
      if (fabsf(d2f - 0.04f) <= 1e-5f) {                                   \
        const double dx = (double)X[p] - (double)(CX);                     \
        const double dy = (double)Y[p] - (double)(CY);                     \
        const double dz = (double)Z[p] - (double)(CZ);                     \
        in = (dx * dx + dy * dy + dz * dz) <= (0.2 * 0.2);                 \
      } else {                                                             \
        in = (d2f < 0.04f);                                                \
      }                                                                    \
      if (in) MASKVAR |= (1u << p);                                        \
    }                                                                      \
  } while (0)

// append up-to-4 hits of one sub-chunk into list Q (static unroll)
#define APPEND4Q(MASKVAR, POSVAR, I0, V0, V1, V2, Q) do {                  \
    if ((MASKVAR) & 1u) { if ((POSVAR) < K_) { sidx[Q][POSVAR] = (I0) + 0; \
      sxyz[Q][POSVAR][0] = (V0).x; sxyz[Q][POSVAR][1] = (V0).y;            \
      sxyz[Q][POSVAR][2] = (V0).z; } ++(POSVAR); }                         \
    if ((MASKVAR) & 2u) { if ((POSVAR) < K_) { sidx[Q][POSVAR] = (I0) + 1; \
      sxyz[Q][POSVAR][0] = (V0).w; sxyz[Q][POSVAR][1] = (V1).x;            \
      sxyz[Q][POSVAR][2] = (V1).y; } ++(POSVAR); }                         \
    if ((MASKVAR) & 4u) { if ((POSVAR) < K_) { sidx[Q][POSVAR] = (I0) + 2; \
      sxyz[Q][POSVAR][0] = (V1).z; sxyz[Q][POSVAR][1] = (V1).w;            \
      sxyz[Q][POSVAR][2] = (V2).x; } ++(POSVAR); }                         \
    if ((MASKVAR) & 8u) { if ((POSVAR) < K_) { sidx[Q][POSVAR] = (I0) + 3; \
      sxyz[Q][POSVAR][0] = (V2).y; sxyz[Q][POSVAR][1] = (V2).z;            \
      sxyz[Q][POSVAR][2] = (V2).w; } ++(POSVAR); }                         \
  } while (0)

// -------- Fused: one wave = 2 queries; joint scan; cached weights ---------
// Joint ball scan (each loaded point tested vs both centers -> scan loads
// ~halved), then weight fragments cached in registers once and reused for
// both MLPs (weight L2 traffic halved). All math verbatim-verified.
__global__ __launch_bounds__(64, 3) void fused_wave2(
    const float* __restrict__ xyz, const float* __restrict__ pf,
    const float* __restrict__ pc,
    const unsigned short* __restrict__ w1p, const float* __restrict__ b1,
    const unsigned short* __restrict__ w2p, const float* __restrict__ b2,
    float* __restrict__ idx_out, float* __restrict__ out)
{
  const int lane = threadIdx.x;                // 0..63
  const int bs0  = blockIdx.x * 2;             // 2 consecutive patches
  const int b    = bs0 >> 10;                  // S_=1024, same batch for both

  __shared__ int   sidx[2][K_];
  __shared__ float sxyz[2][K_][3];
  __shared__ __align__(16) unsigned short Hs[K_][LDH];

  const float* __restrict__ xb  = xyz + (size_t)b * N_ * 3;
  const float* __restrict__ pfb = pf  + (size_t)b * N_ * CSTEM;
  const float cx0 = pc[bs0 * 3 + 0], cy0 = pc[bs0 * 3 + 1], cz0 = pc[bs0 * 3 + 2];
  const float cx1 = pc[bs0 * 3 + 3], cy1 = pc[bs0 * 3 + 4], cz1 = pc[bs0 * 3 + 5];

  // ---- Joint ball scan: 512-pt chunks, prefetched, dual centers ----
  int found0 = 0, found1 = 0;
  {
    const int lo3 = lane * 12;                 // (lane*4)*3 floats
    int base = 0;
    float4 v0 = *(const float4*)&xb[lo3 + 0];
    float4 v1 = *(const float4*)&xb[lo3 + 4];
    float4 v2 = *(const float4*)&xb[lo3 + 8];
    float4 v3 = *(const float4*)&xb[256 * 3 + lo3 + 0];
    float4 v4 = *(const float4*)&xb[256 * 3 + lo3 + 4];
    float4 v5 = *(const float4*)&xb[256 * 3 + lo3 + 8];

    for (;;) {
      const int nb = (base + 512 < N_) ? base + 512 : base;  // clamped prefetch
      const float4 n0 = *(const float4*)&xb[nb * 3 + lo3 + 0];
      const float4 n1 = *(const float4*)&xb[nb * 3 + lo3 + 4];
      const float4 n2 = *(const float4*)&xb[nb * 3 + lo3 + 8];
      const float4 n3 = *(const float4*)&xb[(nb + 256) * 3 + lo3 + 0];
      const float4 n4 = *(const float4*)&xb[(nb + 256) * 3 + lo3 + 4];
      const float4 n5 = *(const float4*)&xb[(nb + 256) * 3 + lo3 + 8];

      unsigned m00 = 0u, m01 = 0u, m10 = 0u, m11 = 0u;
      if (found0 < K_) {                       // wave-uniform skip in tail
        TEST4C(v0, v1, v2, cx0, cy0, cz0, m00);
        TEST4C(v3, v4, v5, cx0, cy0, cz0, m10);
      }
      if (found1 < K_) {
        TEST4C(v0, v1, v2, cx1, cy1, cz1, m01);
        TEST4C(v3, v4, v5, cx1, cy1, cz1, m11);
      }

      const int c00 = __popc(m00), c01 = __popc(m01);
      const int c10 = __popc(m10), c11 = __popc(m11);
      unsigned i0p = (unsigned)c00 | ((unsigned)c01 << 16);  // sub0 packed
      unsigned i1p = (unsigned)c10 | ((unsigned)c11 << 16);  // sub1 packed
      #pragma unroll
      for (int d = 1; d < 64; d <<= 1) {       // dual packed prefix (16b ok)
        const unsigned t0 = (unsigned)__shfl_up((int)i0p, d);
        const unsigned t1 = (unsigned)__shfl_up((int)i1p, d);
        if (lane >= d) { i0p += t0; i1p += t1; }
      }
      const unsigned tot0 = (unsigned)__shfl((int)i0p, 63);
      const unsigned tot1 = (unsigned)__shfl((int)i1p, 63);

      const int i0 = base + lane * 4;
      int pos00 = found0 + (int)(i0p & 0xFFFFu) - c00;
      int pos10 = found0 + (int)(tot0 & 0xFFFFu) + (int)(i1p & 0xFFFFu) - c10;
      int pos01 = found1 + (int)(i0p >> 16) - c01;
      int pos11 = found1 + (int)(tot0 >> 16) + (int)(i1p >> 16) - c11;
      APPEND4Q(m00, pos00, i0,       v0, v1, v2, 0);
      APPEND4Q(m10, pos10, i0 + 256, v3, v4, v5, 0);
      APPEND4Q(m01, pos01, i0,       v0, v1, v2, 1);
      APPEND4Q(m11, pos11, i0 + 256, v3, v4, v5, 1);

      found0 += (int)(tot0 & 0xFFFFu) + (int)(tot1 & 0xFFFFu);
      found1 += (int)(tot0 >> 16) + (int)(tot1 >> 16);
      if (found0 >= K_ && found1 >= K_) break; // wave-uniform
      base += 512;
      if (base >= N_) break;
      v0 = n0; v1 = n1; v2 = n2; v3 = n3; v4 = n4; v5 = n5;
    }
  }

  // ---- Fill (pad with first found; none found -> index N-1) ----
  if (lane == 0) {
    if (found0 == 0) {
      sidx[0][0] = N_ - 1;
      sxyz[0][0][0] = xb[(N_ - 1) * 3 + 0];
      sxyz[0][0][1] = xb[(N_ - 1) * 3 + 1];
      sxyz[0][0][2] = xb[(N_ - 1) * 3 + 2];
    }
    if (found1 == 0) {
      sidx[1][0] = N_ - 1;
      sxyz[1][0][0] = xb[(N_ - 1) * 3 + 0];
      sxyz[1][0][1] = xb[(N_ - 1) * 3 + 1];
      sxyz[1][0][2] = xb[(N_ - 1) * 3 + 2];
    }
  }
  __threadfence_block();

  #pragma unroll
  for (int q = 0; q < 2; ++q) {
    const int fnd = q ? found1 : found0;
    if (lane < K_) {
      const int   fill = sidx[q][0];
      const float fx = sxyz[q][0][0];
      const float fy = sxyz[q][0][1];
      const float fz = sxyz[q][0][2];
      const int v = (lane < fnd) ? sidx[q][lane] : fill;
      if (lane >= fnd) {
        sidx[q][lane] = fill;
        sxyz[q][lane][0] = fx;
        sxyz[q][lane][1] = fy;
        sxyz[q][lane][2] = fz;
      }
      idx_out[(size_t)(bs0 + q) * K_ + lane] = (float)v;
    }
  }
  __threadfence_block();

  // ---- Weight fragments + biases: loaded ONCE, reused for both MLPs ----
  short8v w1f[3][2], w2f[4][2];
  #pragma unroll
  for (int ks = 0; ks < 3; ++ks)
    #pragma unroll
    for (int t = 0; t < 2; ++t)
      w1f[ks][t] = *(const short8v*)&w1p[((size_t)(ks * 8 + 0) * 64 + lane) * 8
                                         + (size_t)(2 * 0 + t) * 0];
  // (re-load below with proper col-chunk indexing inside the loop)
  const int rfr  = lane & 15;
  const int koff = (lane >> 4) * 8;

  // ---- Two MLPs sharing cached weights; col-chunk loop streams chunks ----
  // Weight frags depend on col-chunk c, so cache per (ks,c): 3*2*4 + 4*2*4
  // fragments is too many; instead cache per ks the FULL 8-frag row? That is
  // what streaming was. Compromise: hoist loads of chunk c outside the q
  // loop by restructuring: for each c, load w1/w2 frags once, then compute
  // BOTH queries' partial results for that chunk.
  // L1: acc_q[2][2][2]; L2 requires full Hs per q, so L1 for both q first.
  {
    // A-fragments for both queries
    short8v a0k0[2], a0k1[2], a0k2[2], a1k0[2], a1k1[2], a1k2[2];
    #pragma unroll
    for (int q = 0; q < 2; ++q) {
      const float ccx = q ? cx1 : cx0;
      const float ccy = q ? cy1 : cy0;
      const float ccz = q ? cz1 : cz0;
      const int r0 = sidx[q][rfr];
      const int r1 = sidx[q][16 + rfr];
      const float4 u00 = *(const float4*)&pfb[(size_t)r0 * CSTEM + koff];
      const float4 u01 = *(const float4*)&pfb[(size_t)r0 * CSTEM + koff + 4];
      const float4 u02 = *(const float4*)&pfb[(size_t)r0 * CSTEM + 32 + koff];
      const float4 u03 = *(const float4*)&pfb[(size_t)r0 * CSTEM + 32 + koff + 4];
      const float4 u10 = *(const float4*)&pfb[(size_t)r1 * CSTEM + koff];
      const float4 u11 = *(const float4*)&pfb[(size_t)r1 * CSTEM + koff + 4];
      const float4 u12 = *(const float4*)&pfb[(size_t)r1 * CSTEM + 32 + koff];
      const float4 u13 = *(const float4*)&pfb[(size_t)r1 * CSTEM + 32 + koff + 4];
      a0k0[q] = cvt8(u00, u01); a0k1[q] = cvt8(u02, u03);
      a1k0[q] = cvt8(u10, u11); a1k1[q] = cvt8(u12, u13);
      a0k2[q] = pe_frag(sxyz[q][rfr][0] - ccx, sxyz[q][rfr][1] - ccy,
                        sxyz[q][rfr][2] - ccz, koff);
      a1k2[q] = pe_frag(sxyz[q][16 + rfr][0] - ccx, sxyz[q][16 + rfr][1] - ccy,
                        sxyz[q][16 + rfr][2] - ccz, koff);
    }

    // ---- Layer 1 for BOTH queries per col-chunk (weight frags loaded once)
    // Hs layout: rows 0..31 query0, reuse after L2(q0)... need both Hs before
    // L2 -> process L2 per query sequentially after its own L1. To share
    // weight loads across q for L2 as well, interleave L2 of q0/q1 per chunk.
    // Hs capacity: one query's 32x128. Solve: L1(q0)->Hs, hf0 regs; then
    // L1(q1)->Hs(overwrite, same-wave in-order DS); hf1 regs; L2 both.
    #pragma unroll
    for (int q = 0; q < 2; ++q) {
      #pragma unroll
      for (int c = 0; c < 4; ++c) {
        const short8v bA0 = *(const short8v*)&w1p[((size_t)(0 * 8 + 2 * c + 0) * 64 + lane) * 8];
        const short8v bA1 = *(const short8v*)&w1p[((size_t)(0 * 8 + 2 * c + 1) * 64 + lane) * 8];
        const short8v bB0 = *(const short8v*)&w1p[((size_t)(1 * 8 + 2 * c + 0) * 64 + lane) * 8];
        const short8v bB1 = *(const short8v*)&w1p[((size_t)(1 * 8 + 2 * c + 1) * 64 + lane) * 8];
        const short8v bC0 = *(const short8v*)&w1p[((size_t)(2 * 8 + 2 * c + 0) * 64 + lane) * 8];
        const short8v bC1 = *(const short8v*)&w1p[((size_t)(2 * 8 + 2 * c + 1) * 64 + lane) * 8];

        f32x4 acc[2][2] = {};
        acc[0][0] = __builtin_amdgcn_mfma_f32_16x16x32_bf16(a0k0[q], bA0, acc[0][0], 0, 0, 0);
        acc[0][1] = __builtin_amdgcn_mfma_f32_16x16x32_bf16(a0k0[q], bA1, acc[0][1], 0, 0, 0);
        acc[1][0] = __builtin_amdgcn_mfma_f32_16x16x32_bf16(a1k0[q], bA0, acc[1][0], 0, 0, 0);
        acc[1][1] = __builtin_amdgcn_mfma_f32_16x16x32_bf16(a1k0[q], bA1, acc[1][1], 0, 0, 0);
        acc[0][0] = __builtin_amdgcn_mfma_f32_16x16x32_bf16(a0k1[q], bB0, acc[0][0], 0, 0, 0);
        acc[0][1] = __builtin_amdgcn_mfma_f32_16x16x32_bf16(a0k1[q], bB1, acc[0][1], 0, 0, 0);
        acc[1][0] = __builtin_amdgcn_mfma_f32_16x16x32_bf16(a1k1[q], bB0, acc[1][0], 0, 0, 0);
        acc[1][1] = __builtin_amdgcn_mfma_f32_16x16x32_bf16(a1k1[q], bB1, acc[1][1], 0, 0, 0);
        acc[0][0] = __builtin_amdgcn_mfma_f32_16x16x32_bf16(a0k2[q], bC0, acc[0][0], 0, 0, 0);
        acc[0][1] = __builtin_amdgcn_mfma_f32_16x16x32_bf16(a0k2[q], bC1, acc[0][1], 0, 0, 0);
        acc[1][0] = __builtin_amdgcn_mfma_f32_16x16x32_bf16(a1k2[q], bC0, acc[1][0], 0, 0, 0);
        acc[1][1] = __builtin_amdgcn_mfma_f32_16x16x32_bf16(a1k2[q], bC1, acc[1][1], 0, 0, 0);

        const float bia0 = b1[32 * c + rfr];
        const float bia1 = b1[32 * c + 16 + rfr];
        #pragma unroll
        for (int rt = 0; rt < 2; ++rt)
          #pragma unroll
          for (int reg = 0; reg < 4; ++reg) {
            const int row = 16 * rt + (lane >> 4) * 4 + reg;
            Hs[row][32 * c + rfr]      = f2bf(fmaxf(acc[rt][0][reg] + bia0, 0.f));
            Hs[row][32 * c + 16 + rfr] = f2bf(fmaxf(acc[rt][1][reg] + bia1, 0.f));
          }
      }
      // same-wave LDS round-trip (in-order DS pipe) -> read L2 A-frags
      short8v hf[8];
      #pragma unroll
      for (int ks = 0; ks < 4; ++ks) {
        hf[ks * 2 + 0] = *(const short8v*)&Hs[rfr][ks * 32 + koff];
        hf[ks * 2 + 1] = *(const short8v*)&Hs[16 + rfr][ks * 32 + koff];
      }

      #pragma unroll
      for (int c = 0; c < 4; ++c) {
        f32x4 acc2[2][2] = {};
        #pragma unroll
        for (int ks = 0; ks < 4; ++ks) {
          const short8v b0  = *(const short8v*)&w2p[((size_t)(ks * 8 + 2 * c + 0) * 64 + lane) * 8];
          const short8v b1v = *(const short8v*)&w2p[((size_t)(ks * 8 + 2 * c + 1) * 64 + lane) * 8];
          acc2[0][0] = __builtin_amdgcn_mfma_f32_16x16x32_bf16(hf[ks * 2 + 0], b0,  acc2[0][0], 0, 0, 0);
          acc2[0][1] = __builtin_amdgcn_mfma_f32_16x16x32_bf16(hf[ks * 2 + 0], b1v, acc2[0][1], 0, 0, 0);
          acc2[1][0] = __builtin_amdgcn_mfma_f32_16x16x32_bf16(hf[ks * 2 + 1], b0,  acc2[1][0], 0, 0, 0);
          acc2[1][1] = __builtin_amdgcn_mfma_f32_16x16x32_bf16(hf[ks * 2 + 1], b1v, acc2[1][1], 0, 0, 0);
        }
        float m0 = -3.4e38f, m1 = -3.4e38f;
        #pragma unroll
        for (int rt = 0; rt < 2; ++rt)
          #pragma unroll
          for (int reg = 0; reg < 4; ++reg) {
            m0 = fmaxf(m0, acc2[rt][0][reg]);
            m1 = fmaxf(m1, acc2[rt][1][reg]);
          }
        m0 += b2[32 * c + rfr];
        m1 += b2[32 * c + 16 + rfr];
        m0 = fmaxf(m0, __shfl_xor(m0, 16));
        m0 = fmaxf(m0, __shfl_xor(m0, 32));
        m1 = fmaxf(m1, __shfl_xor(m1, 16));
        m1 = fmaxf(m1, __shfl_xor(m1, 32));
        if (lane < 16) {
          out[(size_t)(bs0 + q) * CPATCH + 32 * c + lane]      = m0;
          out[(size_t)(bs0 + q) * CPATCH + 32 * c + 16 + lane] = m1;
        }
      }
      __threadfence_block();   // drain q0's Hs reads before q1 overwrites
    }
  }
}

extern "C" void kernel_launch(void* const* d_in, const int* in_sizes, int n_in,
                              void* d_out, int out_size, void* d_ws, size_t ws_size,
                              hipStream_t stream) {
  const float* xyz = (const float*)d_in[0];
  const float* pf  = (const float*)d_in[1];
  const float* pc  = (const float*)d_in[2];
  const float* w1  = (const float*)d_in[3];
  const float* b1  = (const float*)d_in[4];
  const float* w2  = (const float*)d_in[5];
  const float* b2  = (const float*)d_in[6];

  float* out     = (float*)d_out;
  float* idx_out = out + (size_t)B_ * S_ * CPATCH;

  unsigned short* w1p = (unsigned short*)d_ws;          // 96*128 bf16
  unsigned short* w2p = w1p + 96 * 128;                 // 128*128 bf16

  pack_weights<<<14, 256, 0, stream>>>(w1, w2, w1p, w2p);
  fused_wave2<<<B_ * S_ / 2, 64, 0, stream>>>(xyz, pf, pc, w1p, b1, w2p, b2,
                                              idx_out, out);
}

// Round 16
// 52.901 us; speedup vs baseline: 1.0810x; 1.0810x over previous
//
#include <hip/hip_runtime.h>
#include <hip/hip_bf16.h>

#define B_ 8
#define N_ 16384
#define S_ 1024
#define K_ 32
#define CSTEM 64
#define CPATCH 128
#define INDIM 91
#define LDA 104     // As row stride (bf16)
#define LDH 136     // Hs row stride (bf16)

typedef __attribute__((ext_vector_type(8))) short short8v;  // 8 bf16 = 4 VGPRs
typedef __attribute__((ext_vector_type(4))) float f32x4;

static __device__ __forceinline__ unsigned short f2bf(float f) {
  union { float f; unsigned int u; } v; v.f = f;
  return (unsigned short)((v.u + 0x7FFFu + ((v.u >> 16) & 1u)) >> 16);  // RNE
}

static __device__ __forceinline__ short8v cvt8(const float4 a, const float4 b) {
  unsigned short v[8];
  v[0] = f2bf(a.x); v[1] = f2bf(a.y); v[2] = f2bf(a.z); v[3] = f2bf(a.w);
  v[4] = f2bf(b.x); v[5] = f2bf(b.y); v[6] = f2bf(b.z); v[7] = f2bf(b.w);
  return *(const short8v*)v;
}

// -------- Kernel 0: pack w1/w2 into MFMA B-fragment order (bf16) --------
__global__ __launch_bounds__(256) void pack_weights(
    const float* __restrict__ w1, const float* __restrict__ w2,
    unsigned short* __restrict__ w1p, unsigned short* __restrict__ w2p)
{
  const int id = blockIdx.x * 256 + threadIdx.x;
  if (id < 3 * 8 * 64) {                       // w1: K padded 91->96 (3 ksteps)
    const int l = id & 63, ct = (id >> 6) & 7, ks = id >> 9;
    const int col = 16 * ct + (l & 15);
    const int kb = 32 * ks + (l >> 4) * 8;
    unsigned short v[8];
    #pragma unroll
    for (int j = 0; j < 8; ++j) {
      const int k = kb + j;
      v[j] = (k < INDIM) ? f2bf(w1[k * CPATCH + col]) : (unsigned short)0;
    }
    *(short8v*)&w1p[(size_t)id * 8] = *(const short8v*)v;
  } else if (id < 3 * 8 * 64 + 4 * 8 * 64) {   // w2: 4 ksteps
    const int id2 = id - 3 * 8 * 64;
    const int l = id2 & 63, ct = (id2 >> 6) & 7, ks = id2 >> 9;
    const int col = 16 * ct + (l & 15);
    const int kb = 32 * ks + (l >> 4) * 8;
    unsigned short v[8];
    #pragma unroll
    for (int j = 0; j < 8; ++j) v[j] = f2bf(w2[(kb + j) * CPATCH + col]);
    *(short8v*)&w2p[(size_t)id2 * 8] = *(const short8v*)v;
  }
}

// test 4 consecutive points packed in 3 float4 (R3/R7/R14-verified) vs center
#define TEST4(V0, V1, V2, MASKVAR) do {                                    \
    MASKVAR = 0u;                                                          \
    const float X[4] = {(V0).x, (V0).w, (V1).z, (V2).y};                   \
    const float Y[4] = {(V0).y, (V1).x, (V1).w, (V2).z};                   \
    const float Z[4] = {(V0).z, (V1).y, (V2).x, (V2).w};                   \
    _Pragma("unroll")                                                      \
    for (int p = 0; p < 4; ++p) {                                          \
      const float dxf = X[p] - cx, dyf = Y[p] - cy, dzf = Z[p] - cz;       \
      const float d2f = fmaf(dxf, dxf, fmaf(dyf, dyf, dzf * dzf));         \
      bool in;                                                             \
      if (fabsf(d2f - 0.04f) <= 1e-5f) {                                   \
        const double dx = (double)X[p] - (double)cx;                       \
        const double dy = (double)Y[p] - (double)cy;                       \
        const double dz = (double)Z[p] - (double)cz;                       \
        in = (dx * dx + dy * dy + dz * dz) <= (0.2 * 0.2);                 \
      } else {                                                             \
        in = (d2f < 0.04f);                                                \
      }                                                                    \
      if (in) MASKVAR |= (1u << p);                                        \
    }                                                                      \
  } while (0)

#define APPEND4(MASKVAR, POSVAR, I0, V0, V1, V2) do {                      \
    if ((MASKVAR) & 1u) { if ((POSVAR) < K_) { sidx[POSVAR] = (I0) + 0;    \
      sxyz[POSVAR][0] = (V0).x; sxyz[POSVAR][1] = (V0).y;                  \
      sxyz[POSVAR][2] = (V0).z; } ++(POSVAR); }                            \
    if ((MASKVAR) & 2u) { if ((POSVAR) < K_) { sidx[POSVAR] = (I0) + 1;    \
      sxyz[POSVAR][0] = (V0).w; sxyz[POSVAR][1] = (V1).x;                  \
      sxyz[POSVAR][2] = (V1).y; } ++(POSVAR); }                            \
    if ((MASKVAR) & 4u) { if ((POSVAR) < K_) { sidx[POSVAR] = (I0) + 2;    \
      sxyz[POSVAR][0] = (V1).z; sxyz[POSVAR][1] = (V1).w;                  \
      sxyz[POSVAR][2] = (V2).x; } ++(POSVAR); }                            \
    if ((MASKVAR) & 8u) { if ((POSVAR) < K_) { sidx[POSVAR] = (I0) + 3;    \
      sxyz[POSVAR][0] = (V2).y; sxyz[POSVAR][1] = (V2).z;                  \
      sxyz[POSVAR][2] = (V2).w; } ++(POSVAR); }                            \
  } while (0)

// -------- Kernel 1: ball query only (R14-verified loop), coords -> ws -----
__global__ __launch_bounds__(64, 4) void ball_kernel(
    const float* __restrict__ xyz, const float* __restrict__ pc,
    float* __restrict__ idx_out, float* __restrict__ xws)
{
  const int lane = threadIdx.x;                // 0..63
  const int bs   = blockIdx.x;
  const int b    = bs >> 10;                   // S_ = 1024

  __shared__ int   sidx[K_];
  __shared__ float sxyz[K_][3];

  const float* __restrict__ xb = xyz + (size_t)b * N_ * 3;
  const float cx = pc[bs * 3 + 0];
  const float cy = pc[bs * 3 + 1];
  const float cz = pc[bs * 3 + 2];

  int found = 0;
  {
    const int lo3 = lane * 12;                 // (lane*4)*3 floats
    int base = 0;
    float4 v0 = *(const float4*)&xb[lo3 + 0];
    float4 v1 = *(const float4*)&xb[lo3 + 4];
    float4 v2 = *(const float4*)&xb[lo3 + 8];
    float4 v3 = *(const float4*)&xb[256 * 3 + lo3 + 0];
    float4 v4 = *(const float4*)&xb[256 * 3 + lo3 + 4];
    float4 v5 = *(const float4*)&xb[256 * 3 + lo3 + 8];

    for (;;) {
      const int nb = (base + 512 < N_) ? base + 512 : base;  // clamped prefetch
      const float4 n0 = *(const float4*)&xb[nb * 3 + lo3 + 0];
      const float4 n1 = *(const float4*)&xb[nb * 3 + lo3 + 4];
      const float4 n2 = *(const float4*)&xb[nb * 3 + lo3 + 8];
      const float4 n3 = *(const float4*)&xb[(nb + 256) * 3 + lo3 + 0];
      const float4 n4 = *(const float4*)&xb[(nb + 256) * 3 + lo3 + 4];
      const float4 n5 = *(const float4*)&xb[(nb + 256) * 3 + lo3 + 8];

      unsigned m0, m1;
      TEST4(v0, v1, v2, m0);
      TEST4(v3, v4, v5, m1);

      const int c0 = __popc(m0), c1 = __popc(m1);
      unsigned incl = (unsigned)c0 | ((unsigned)c1 << 16);
      #pragma unroll
      for (int d = 1; d < 64; d <<= 1) {
        const unsigned t = (unsigned)__shfl_up((int)incl, d);
        if (lane >= d) incl += t;
      }
      const unsigned tot = (unsigned)__shfl((int)incl, 63);
      const int t0 = (int)(tot & 0xFFFFu), t1 = (int)(tot >> 16);

      int pos0 = found + (int)(incl & 0xFFFFu) - c0;
      int pos1 = found + t0 + (int)(incl >> 16) - c1;
      const int i0 = base + lane * 4;
      APPEND4(m0, pos0, i0, v0, v1, v2);
      APPEND4(m1, pos1, i0 + 256, v3, v4, v5);

      found += t0 + t1;
      if (found >= K_) break;                  // wave-uniform
      base += 512;
      if (base >= N_) break;
      v0 = n0; v1 = n1; v2 = n2; v3 = n3; v4 = n4; v5 = n5;
    }
  }

  if (lane == 0 && found == 0) {               // none found -> index N-1
    sidx[0] = N_ - 1;
    sxyz[0][0] = xb[(N_ - 1) * 3 + 0];
    sxyz[0][1] = xb[(N_ - 1) * 3 + 1];
    sxyz[0][2] = xb[(N_ - 1) * 3 + 2];
  }
  __threadfence_block();

  if (lane < K_) {                             // pad with first found
    const int   fill = sidx[0];
    const float fx = sxyz[0][0];
    const float fy = sxyz[0][1];
    const float fz = sxyz[0][2];
    const int v = (lane < found) ? sidx[lane] : fill;
    const float x = (lane < found) ? sxyz[lane][0] : fx;
    const float y = (lane < found) ? sxyz[lane][1] : fy;
    const float z = (lane < found) ? sxyz[lane][2] : fz;
    idx_out[(size_t)bs * K_ + lane] = (float)v;
    xws[((size_t)bs * K_ + lane) * 3 + 0] = x;
    xws[((size_t)bs * K_ + lane) * 3 + 1] = y;
    xws[((size_t)bs * K_ + lane) * 3 + 2] = z;
  }
}

// -------- Kernel 2: persistent pipelined MLP (512 blocks, 16 patches ea) --
// Per group of 4 patches: write staged regs->As, barrier, ISSUE next group's
// pf gathers (latency hides under MFMA), compute 4 patches (R9-verified
// body: cached weight frags, Hs roundtrip, column max).
__global__ __launch_bounds__(256, 2) void mlp_persist(
    const float* __restrict__ pf, const float* __restrict__ pc,
    const unsigned short* __restrict__ w1p, const float* __restrict__ b1,
    const unsigned short* __restrict__ w2p, const float* __restrict__ b2,
    const float* __restrict__ idx_f, const float* __restrict__ xws,
    float* __restrict__ out)
{
  const int tid  = threadIdx.x;
  const int lane = tid & 63;
  const int w    = tid >> 6;
  const int p0   = blockIdx.x * 16;            // 16 consecutive patches
  const int b    = p0 >> 10;                   // same batch (1024 % 16 == 0)

  __shared__ __align__(16) unsigned short As[4 * K_][LDA];
  __shared__ __align__(16) unsigned short Hs[K_][LDH];
  __shared__ int   sidxAll[16][K_];
  __shared__ float sxyzAll[16][K_][3];
  __shared__ float scenAll[16][3];

  const float* __restrict__ pfb = pf + (size_t)b * N_ * CSTEM;

  // ---- Prologue: stage idx/coords/centers for all 16 patches ----
  #pragma unroll
  for (int t = tid; t < 16 * K_; t += 256)
    ((int*)sidxAll)[t] = (int)idx_f[(size_t)p0 * K_ + t];
  #pragma unroll
  for (int t = tid; t < 16 * K_ * 3; t += 256)
    ((float*)sxyzAll)[t] = xws[(size_t)p0 * K_ * 3 + t];
  if (tid < 48) ((float*)scenAll)[tid] = pc[p0 * 3 + tid];

  // ---- Weight fragments + biases: cached once, reused for 16 patches ----
  short8v w1f[3][2], w2f[4][2];
  #pragma unroll
  for (int ks = 0; ks < 3; ++ks)
    #pragma unroll
    for (int t = 0; t < 2; ++t)
      w1f[ks][t] = *(const short8v*)&w1p[((size_t)(ks * 8 + 2 * w + t) * 64 + lane) * 8];
  #pragma unroll
  for (int ks = 0; ks < 4; ++ks)
    #pragma unroll
    for (int t = 0; t < 2; ++t)
      w2f[ks][t] = *(const short8v*)&w2p[((size_t)(ks * 8 + 2 * w + t) * 64 + lane) * 8];
  const float bias1[2] = { b1[32 * w + (lane & 15)], b1[32 * w + 16 + (lane & 15)] };
  const float bias2[2] = { b2[32 * w + (lane & 15)], b2[32 * w + 16 + (lane & 15)] };
  __syncthreads();

  const int row1 = tid >> 3, sub = tid & 7;    // phase-1 map (features)
  const int row2 = tid & 31, j2 = tid >> 5;    // phase-2 map (rel+PE)

  // ---- Stage group 0's pf gathers into registers ----
  float4 f0a[4], f1a[4];
  #pragma unroll
  for (int q = 0; q < 4; ++q) {
    const int r = sidxAll[q][row1];
    f0a[q] = *(const float4*)&pfb[(size_t)r * CSTEM + sub * 8];
    f1a[q] = *(const float4*)&pfb[(size_t)r * CSTEM + sub * 8 + 4];
  }

  #pragma unroll 1
  for (int g = 0; g < 4; ++g) {
    // step 1: write staged regs + phase-2 PE into As (As free: last group's
    // final barrier covered all reads)
    #pragma unroll
    for (int q = 0; q < 4; ++q)
      *(short8v*)&As[q * K_ + row1][sub * 8] = cvt8(f0a[q], f1a[q]);
    #pragma unroll
    for (int q = 0; q < 4; ++q) {
      const int p = g * 4 + q;
      const float r0 = sxyzAll[p][row2][0] - scenAll[p][0];
      const float r1 = sxyzAll[p][row2][1] - scenAll[p][1];
      const float r2 = sxyzAll[p][row2][2] - scenAll[p][2];
      #pragma unroll
      for (int cc = 0; cc < 4; ++cc) {
        const int c = 64 + 4 * j2 + cc;
        float val;
        if (c < 67) val = (c == 64) ? r0 : ((c == 65) ? r1 : r2);
        else if (c < 91) {
          const int qq = c - 67, d = qq >> 3, rbit = qq & 7, band = rbit & 3;
          const float rel = (d == 0) ? r0 : ((d == 1) ? r1 : r2);
          const float ang = rel * ((float)(1 << band) * 3.14159265358979323846f);
          val = (rbit < 4) ? __sinf(ang) : __cosf(ang);
        } else val = 0.f;
        As[q * K_ + row2][c] = f2bf(val);
      }
    }
    __syncthreads();

    // step 2: ISSUE next group's gathers (complete during MFMA below)
    if (g < 3) {
      #pragma unroll
      for (int q = 0; q < 4; ++q) {
        const int r = sidxAll[(g + 1) * 4 + q][row1];
        f0a[q] = *(const float4*)&pfb[(size_t)r * CSTEM + sub * 8];
        f1a[q] = *(const float4*)&pfb[(size_t)r * CSTEM + sub * 8 + 4];
      }
    }

    // step 3: compute 4 patches (R9-verified body)
    #pragma unroll 1
    for (int q = 0; q < 4; ++q) {
      f32x4 acc[2][2] = {};
      #pragma unroll
      for (int ks = 0; ks < 3; ++ks) {
        const int k0 = ks * 32 + (lane >> 4) * 8;
        const short8v a0 = *(const short8v*)&As[q * K_ + (lane & 15)][k0];
        const short8v a1 = *(const short8v*)&As[q * K_ + 16 + (lane & 15)][k0];
        acc[0][0] = __builtin_amdgcn_mfma_f32_16x16x32_bf16(a0, w1f[ks][0], acc[0][0], 0, 0, 0);
        acc[0][1] = __builtin_amdgcn_mfma_f32_16x16x32_bf16(a0, w1f[ks][1], acc[0][1], 0, 0, 0);
        acc[1][0] = __builtin_amdgcn_mfma_f32_16x16x32_bf16(a1, w1f[ks][0], acc[1][0], 0, 0, 0);
        acc[1][1] = __builtin_amdgcn_mfma_f32_16x16x32_bf16(a1, w1f[ks][1], acc[1][1], 0, 0, 0);
      }
      #pragma unroll
      for (int rt = 0; rt < 2; ++rt)
        #pragma unroll
        for (int t = 0; t < 2; ++t)
          #pragma unroll
          for (int reg = 0; reg < 4; ++reg) {
            const float h = fmaxf(acc[rt][t][reg] + bias1[t], 0.f);
            const int row = 16 * rt + (lane >> 4) * 4 + reg;
            const int col = 32 * w + 16 * t + (lane & 15);
            Hs[row][col] = f2bf(h);
          }
      __syncthreads();

      f32x4 acc2[2][2] = {};
      #pragma unroll
      for (int ks = 0; ks < 4; ++ks) {
        const int k0 = ks * 32 + (lane >> 4) * 8;
        const short8v a0 = *(const short8v*)&Hs[(lane & 15)][k0];
        const short8v a1 = *(const short8v*)&Hs[16 + (lane & 15)][k0];
        acc2[0][0] = __builtin_amdgcn_mfma_f32_16x16x32_bf16(a0, w2f[ks][0], acc2[0][0], 0, 0, 0);
        acc2[0][1] = __builtin_amdgcn_mfma_f32_16x16x32_bf16(a0, w2f[ks][1], acc2[0][1], 0, 0, 0);
        acc2[1][0] = __builtin_amdgcn_mfma_f32_16x16x32_bf16(a1, w2f[ks][0], acc2[1][0], 0, 0, 0);
        acc2[1][1] = __builtin_amdgcn_mfma_f32_16x16x32_bf16(a1, w2f[ks][1], acc2[1][1], 0, 0, 0);
      }
      float m0 = -3.4e38f, m1 = -3.4e38f;
      #pragma unroll
      for (int rt = 0; rt < 2; ++rt)
        #pragma unroll
        for (int reg = 0; reg < 4; ++reg) {
          m0 = fmaxf(m0, acc2[rt][0][reg]);
          m1 = fmaxf(m1, acc2[rt][1][reg]);
        }
      m0 += bias2[0];
      m1 += bias2[1];
      m0 = fmaxf(m0, __shfl_xor(m0, 16));
      m0 = fmaxf(m0, __shfl_xor(m0, 32));
      m1 = fmaxf(m1, __shfl_xor(m1, 16));
      m1 = fmaxf(m1, __shfl_xor(m1, 32));
      if (lane < 16) {
        const int bs = p0 + g * 4 + q;
        out[(size_t)bs * CPATCH + 32 * w + lane]      = m0;
        out[(size_t)bs * CPATCH + 32 * w + 16 + lane] = m1;
      }
      __syncthreads();                         // Hs (and last-q As) protect
    }
  }
}

extern "C" void kernel_launch(void* const* d_in, const int* in_sizes, int n_in,
                              void* d_out, int out_size, void* d_ws, size_t ws_size,
                              hipStream_t stream) {
  const float* xyz = (const float*)d_in[0];
  const float* pf  = (const float*)d_in[1];
  const float* pc  = (const float*)d_in[2];
  const float* w1  = (const float*)d_in[3];
  const float* b1  = (const float*)d_in[4];
  const float* w2  = (const float*)d_in[5];
  const float* b2  = (const float*)d_in[6];

  float* out     = (float*)d_out;
  float* idx_out = out + (size_t)B_ * S_ * CPATCH;

  float* xws = (float*)d_ws;                             // 8192*32*3 f32 = 3MB
  unsigned short* w1p = (unsigned short*)(xws + (size_t)B_ * S_ * K_ * 3);
  unsigned short* w2p = w1p + 96 * 128;

  pack_weights<<<14, 256, 0, stream>>>(w1, w2, w1p, w2p);
  ball_kernel<<<B_ * S_, 64, 0, stream>>>(xyz, pc, idx_out, xws);
  mlp_persist<<<B_ * S_ / 16, 256, 0, stream>>>(pf, pc, w1p, b1, w2p, b2,
                                                idx_out, xws, out);
}

// Round 17
// 45.829 us; speedup vs baseline: 1.2478x; 1.1543x over previous
//
#include <hip/hip_runtime.h>
#include <hip/hip_bf16.h>

#define B_ 8
#define N_ 16384
#define S_ 1024
#define K_ 32
#define CSTEM 64
#define CPATCH 128
#define INDIM 91
#define LDH 136     // Hs row stride (bf16): 272B -> 2-way (free)

typedef __attribute__((ext_vector_type(8))) short short8v;  // 8 bf16 = 4 VGPRs
typedef __attribute__((ext_vector_type(4))) float f32x4;

static __device__ __forceinline__ unsigned short f2bf(float f) {
  union { float f; unsigned int u; } v; v.f = f;
  return (unsigned short)((v.u + 0x7FFFu + ((v.u >> 16) & 1u)) >> 16);  // RNE
}

static __device__ __forceinline__ short8v cvt8(const float4 a, const float4 b) {
  unsigned short v[8];
  v[0] = f2bf(a.x); v[1] = f2bf(a.y); v[2] = f2bf(a.z); v[3] = f2bf(a.w);
  v[4] = f2bf(b.x); v[5] = f2bf(b.y); v[6] = f2bf(b.z); v[7] = f2bf(b.w);
  return *(const short8v*)v;
}

// PE/rel fragment (verified R8-R16 numerics)
static __device__ __forceinline__ short8v pe_frag(
    float r0, float r1, float r2, int kq)
{
  unsigned short v[8];
  #pragma unroll
  for (int j = 0; j < 8; ++j) {
    const int c = 64 + kq + j;
    float val;
    if (c < 67) {
      val = (c == 64) ? r0 : ((c == 65) ? r1 : r2);
    } else if (c < 91) {
      const int qq = c - 67, d = qq >> 3, rbit = qq & 7, band = rbit & 3;
      const float rel = (d == 0) ? r0 : ((d == 1) ? r1 : r2);
      const float ang = rel * ((float)(1 << band) * 3.14159265358979323846f);
      val = (rbit < 4) ? __sinf(ang) : __cosf(ang);
    } else {
      val = 0.f;
    }
    v[j] = f2bf(val);
  }
  return *(const short8v*)v;
}

// -------- Kernel 0: pack w1/w2 into MFMA B-fragment order (bf16) --------
__global__ __launch_bounds__(256) void pack_weights(
    const float* __restrict__ w1, const float* __restrict__ w2,
    unsigned short* __restrict__ w1p, unsigned short* __restrict__ w2p)
{
  const int id = blockIdx.x * 256 + threadIdx.x;
  if (id < 3 * 8 * 64) {                       // w1: K padded 91->96 (3 ksteps)
    const int l = id & 63, ct = (id >> 6) & 7, ks = id >> 9;
    const int col = 16 * ct + (l & 15);
    const int kb = 32 * ks + (l >> 4) * 8;
    unsigned short v[8];
    #pragma unroll
    for (int j = 0; j < 8; ++j) {
      const int k = kb + j;
      v[j] = (k < INDIM) ? f2bf(w1[k * CPATCH + col]) : (unsigned short)0;
    }
    *(short8v*)&w1p[(size_t)id * 8] = *(const short8v*)v;
  } else if (id < 3 * 8 * 64 + 4 * 8 * 64) {   // w2: 4 ksteps
    const int id2 = id - 3 * 8 * 64;
    const int l = id2 & 63, ct = (id2 >> 6) & 7, ks = id2 >> 9;
    const int col = 16 * ct + (l & 15);
    const int kb = 32 * ks + (l >> 4) * 8;
    unsigned short v[8];
    #pragma unroll
    for (int j = 0; j < 8; ++j) v[j] = f2bf(w2[(kb + j) * CPATCH + col]);
    *(short8v*)&w2p[(size_t)id2 * 8] = *(const short8v*)v;
  }
}

// f32-only test of 4 consecutive points (R3/R7/R14-verified component map);
// also produces a "band" mask of points needing exact f64 recheck.
#define TEST4FB(V0, V1, V2, MASKVAR, BANDVAR) do {                         \
    MASKVAR = 0u; BANDVAR = 0u;                                            \
    const float X[4] = {(V0).x, (V0).w, (V1).z, (V2).y};                   \
    const float Y[4] = {(V0).y, (V1).x, (V1).w, (V2).z};                   \
    const float Z[4] = {(V0).z, (V1).y, (V2).x, (V2).w};                   \
    _Pragma("unroll")                                                      \
    for (int p = 0; p < 4; ++p) {                                          \
      const float dxf = X[p] - cx, dyf = Y[p] - cy, dzf = Z[p] - cz;       \
      const float d2f = fmaf(dxf, dxf, fmaf(dyf, dyf, dzf * dzf));         \
      if (fabsf(d2f - 0.04f) <= 1e-5f) BANDVAR |= (1u << p);               \
      if (d2f < 0.04f) MASKVAR |= (1u << p);                               \
    }                                                                      \
  } while (0)

// exact f64 fixup for band points (verified expression, decision-identical)
#define FIX4(BANDVAR, MASKVAR, V0, V1, V2) do {                            \
    if (BANDVAR) {                                                         \
      const float X[4] = {(V0).x, (V0).w, (V1).z, (V2).y};                 \
      const float Y[4] = {(V0).y, (V1).x, (V1).w, (V2).z};                 \
      const float Z[4] = {(V0).z, (V1).y, (V2).x, (V2).w};                 \
      _Pragma("unroll")                                                    \
      for (int p = 0; p < 4; ++p) {                                        \
        if ((BANDVAR >> p) & 1u) {                                         \
          const double dx = (double)X[p] - (double)cx;                     \
          const double dy = (double)Y[p] - (double)cy;                     \
          const double dz = (double)Z[p] - (double)cz;                     \
          const bool in64 = (dx * dx + dy * dy + dz * dz) <= (0.2 * 0.2);  \
          MASKVAR = (MASKVAR & ~(1u << p)) | ((unsigned)in64 << p);        \
        }                                                                  \
      }                                                                    \
    }                                                                      \
  } while (0)

#define APPEND4(MASKVAR, POSVAR, I0, V0, V1, V2) do {                      \
    if ((MASKVAR) & 1u) { if ((POSVAR) < K_) { sidx[POSVAR] = (I0) + 0;    \
      sxyz[POSVAR][0] = (V0).x; sxyz[POSVAR][1] = (V0).y;                  \
      sxyz[POSVAR][2] = (V0).z; } ++(POSVAR); }                            \
    if ((MASKVAR) & 2u) { if ((POSVAR) < K_) { sidx[POSVAR] = (I0) + 1;    \
      sxyz[POSVAR][0] = (V0).w; sxyz[POSVAR][1] = (V1).x;                  \
      sxyz[POSVAR][2] = (V1).y; } ++(POSVAR); }                            \
    if ((MASKVAR) & 4u) { if ((POSVAR) < K_) { sidx[POSVAR] = (I0) + 2;    \
      sxyz[POSVAR][0] = (V1).z; sxyz[POSVAR][1] = (V1).w;                  \
      sxyz[POSVAR][2] = (V2).x; } ++(POSVAR); }                            \
    if ((MASKVAR) & 8u) { if ((POSVAR) < K_) { sidx[POSVAR] = (I0) + 3;    \
      sxyz[POSVAR][0] = (V2).y; sxyz[POSVAR][1] = (V2).z;                  \
      sxyz[POSVAR][2] = (V2).w; } ++(POSVAR); }                            \
  } while (0)

#define LDW1(KS, C, T) \
  (*(const short8v*)&w1p[((size_t)((KS) * 8 + 2 * (C) + (T)) * 64 + lane) * 8])
#define LDW2(KS, C, T) \
  (*(const short8v*)&w2p[((size_t)((KS) * 8 + 2 * (C) + (T)) * 64 + lane) * 8])

// -------- Fused, one wave = one query (R14 champion + 3 surgical fixes) ---
__global__ __launch_bounds__(64, 4) void fused_wave(
    const float* __restrict__ xyz, const float* __restrict__ pf,
    const float* __restrict__ pc,
    const unsigned short* __restrict__ w1p, const float* __restrict__ b1,
    const unsigned short* __restrict__ w2p, const float* __restrict__ b2,
    float* __restrict__ idx_out, float* __restrict__ out)
{
  const int lane = threadIdx.x;                // 0..63
  const int bs   = blockIdx.x;
  const int b    = bs >> 10;                   // S_ = 1024

  __shared__ int   sidx[K_];
  __shared__ float sxyz[K_][3];
  __shared__ __align__(16) unsigned short Hs[K_][LDH];

  const float* __restrict__ xb  = xyz + (size_t)b * N_ * 3;
  const float* __restrict__ pfb = pf  + (size_t)b * N_ * CSTEM;
  const float cx = pc[bs * 3 + 0];
  const float cy = pc[bs * 3 + 1];
  const float cz = pc[bs * 3 + 2];

  // ---- Ball scan: 512-pt chunks, prefetched; f32 test + rare f64 fixup ----
  int found = 0;
  {
    const int lo3 = lane * 12;                 // (lane*4)*3 floats
    int base = 0;
    float4 v0 = *(const float4*)&xb[lo3 + 0];
    float4 v1 = *(const float4*)&xb[lo3 + 4];
    float4 v2 = *(const float4*)&xb[lo3 + 8];
    float4 v3 = *(const float4*)&xb[256 * 3 + lo3 + 0];
    float4 v4 = *(const float4*)&xb[256 * 3 + lo3 + 4];
    float4 v5 = *(const float4*)&xb[256 * 3 + lo3 + 8];

    for (;;) {
      const int nb = (base + 512 < N_) ? base + 512 : base;  // clamped prefetch
      const float4 n0 = *(const float4*)&xb[nb * 3 + lo3 + 0];
      const float4 n1 = *(const float4*)&xb[nb * 3 + lo3 + 4];
      const float4 n2 = *(const float4*)&xb[nb * 3 + lo3 + 8];
      const float4 n3 = *(const float4*)&xb[(nb + 256) * 3 + lo3 + 0];
      const float4 n4 = *(const float4*)&xb[(nb + 256) * 3 + lo3 + 4];
      const float4 n5 = *(const float4*)&xb[(nb + 256) * 3 + lo3 + 8];

      unsigned m0, m1, bd0, bd1;
      TEST4FB(v0, v1, v2, m0, bd0);
      TEST4FB(v3, v4, v5, m1, bd1);
      if (__any((int)(bd0 | bd1))) {           // wave-uniform, ~1.5% of iters
        FIX4(bd0, m0, v0, v1, v2);
        FIX4(bd1, m1, v3, v4, v5);
      }

      const int c0 = __popc(m0), c1 = __popc(m1);
      unsigned incl = (unsigned)c0 | ((unsigned)c1 << 16);
      #pragma unroll
      for (int d = 1; d < 64; d <<= 1) {       // packed dual prefix
        const unsigned t = (unsigned)__shfl_up((int)incl, d);
        if (lane >= d) incl += t;
      }
      const unsigned tot = (unsigned)__shfl((int)incl, 63);
      const int t0 = (int)(tot & 0xFFFFu), t1 = (int)(tot >> 16);

      int pos0 = found + (int)(incl & 0xFFFFu) - c0;
      int pos1 = found + t0 + (int)(incl >> 16) - c1;
      const int i0 = base + lane * 4;
      APPEND4(m0, pos0, i0, v0, v1, v2);
      APPEND4(m1, pos1, i0 + 256, v3, v4, v5);

      found += t0 + t1;
      if (found >= K_) break;                  // wave-uniform
      base += 512;
      if (base >= N_) break;
      v0 = n0; v1 = n1; v2 = n2; v3 = n3; v4 = n4; v5 = n5;
    }
  }

  if (lane == 0 && found == 0) {               // none found -> index N-1
    sidx[0] = N_ - 1;
    sxyz[0][0] = xb[(N_ - 1) * 3 + 0];
    sxyz[0][1] = xb[(N_ - 1) * 3 + 1];
    sxyz[0][2] = xb[(N_ - 1) * 3 + 2];
  }
  __threadfence_block();

  // ---- Register-selected padding (no LDS write-back round trip) ----
  const int rfr  = lane & 15;
  const int koff = (lane >> 4) * 8;            // 0,8,16,24

  const int r0 = (rfr < found)      ? sidx[rfr]      : sidx[0];
  const int r1 = (16 + rfr < found) ? sidx[16 + rfr] : sidx[0];

  // issue pf gathers IMMEDIATELY (latency hides under everything below)
  const float4 u00 = *(const float4*)&pfb[(size_t)r0 * CSTEM + koff];
  const float4 u01 = *(const float4*)&pfb[(size_t)r0 * CSTEM + koff + 4];
  const float4 u02 = *(const float4*)&pfb[(size_t)r0 * CSTEM + 32 + koff];
  const float4 u03 = *(const float4*)&pfb[(size_t)r0 * CSTEM + 32 + koff + 4];
  const float4 u10 = *(const float4*)&pfb[(size_t)r1 * CSTEM + koff];
  const float4 u11 = *(const float4*)&pfb[(size_t)r1 * CSTEM + koff + 4];
  const float4 u12 = *(const float4*)&pfb[(size_t)r1 * CSTEM + 32 + koff];
  const float4 u13 = *(const float4*)&pfb[(size_t)r1 * CSTEM + 32 + koff + 4];

  if (lane < K_) {                             // idx output (padded)
    const int vout = (lane < found) ? sidx[lane] : sidx[0];
    idx_out[(size_t)bs * K_ + lane] = (float)vout;
  }

  // padded coords via register selects
  const float sxa = (rfr < found) ? sxyz[rfr][0] : sxyz[0][0];
  const float sya = (rfr < found) ? sxyz[rfr][1] : sxyz[0][1];
  const float sza = (rfr < found) ? sxyz[rfr][2] : sxyz[0][2];
  const float sxb2 = (16 + rfr < found) ? sxyz[16 + rfr][0] : sxyz[0][0];
  const float syb2 = (16 + rfr < found) ? sxyz[16 + rfr][1] : sxyz[0][1];
  const float szb2 = (16 + rfr < found) ? sxyz[16 + rfr][2] : sxyz[0][2];

  const short8v a0k2 = pe_frag(sxa - cx, sya - cy, sza - cz, koff);
  const short8v a1k2 = pe_frag(sxb2 - cx, syb2 - cy, szb2 - cz, koff);
  const short8v a0k0 = cvt8(u00, u01), a0k1 = cvt8(u02, u03);
  const short8v a1k0 = cvt8(u10, u11), a1k1 = cvt8(u12, u13);

  // ---- Layer 1: double-buffered weight sets (load c+1 during MFMA c) ----
  short8v wA0, wA1, wB0, wB1, wC0, wC1;        // current set
  short8v xA0, xA1, xB0, xB1, xC0, xC1;        // next set
  wA0 = LDW1(0, 0, 0); wA1 = LDW1(0, 0, 1);
  wB0 = LDW1(1, 0, 0); wB1 = LDW1(1, 0, 1);
  wC0 = LDW1(2, 0, 0); wC1 = LDW1(2, 0, 1);

#define L1_CHUNK(C, A0,A1,B0,B1,C0,C1, P0,P1,P2,P3,P4,P5, PREF)            \
  do {                                                                     \
    if (PREF) {                                                            \
      P0 = LDW1(0, (C) + 1, 0); P1 = LDW1(0, (C) + 1, 1);                  \
      P2 = LDW1(1, (C) + 1, 0); P3 = LDW1(1, (C) + 1, 1);                  \
      P4 = LDW1(2, (C) + 1, 0); P5 = LDW1(2, (C) + 1, 1);                  \
    }                                                                      \
    f32x4 acc[2][2] = {};                                                  \
    acc[0][0] = __builtin_amdgcn_mfma_f32_16x16x32_bf16(a0k0, A0, acc[0][0], 0, 0, 0); \
    acc[0][1] = __builtin_amdgcn_mfma_f32_16x16x32_bf16(a0k0, A1, acc[0][1], 0, 0, 0); \
    acc[1][0] = __builtin_amdgcn_mfma_f32_16x16x32_bf16(a1k0, A0, acc[1][0], 0, 0, 0); \
    acc[1][1] = __builtin_amdgcn_mfma_f32_16x16x32_bf16(a1k0, A1, acc[1][1], 0, 0, 0); \
    acc[0][0] = __builtin_amdgcn_mfma_f32_16x16x32_bf16(a0k1, B0, acc[0][0], 0, 0, 0); \
    acc[0][1] = __builtin_amdgcn_mfma_f32_16x16x32_bf16(a0k1, B1, acc[0][1], 0, 0, 0); \
    acc[1][0] = __builtin_amdgcn_mfma_f32_16x16x32_bf16(a1k1, B0, acc[1][0], 0, 0, 0); \
    acc[1][1] = __builtin_amdgcn_mfma_f32_16x16x32_bf16(a1k1, B1, acc[1][1], 0, 0, 0); \
    acc[0][0] = __builtin_amdgcn_mfma_f32_16x16x32_bf16(a0k2, C0, acc[0][0], 0, 0, 0); \
    acc[0][1] = __builtin_amdgcn_mfma_f32_16x16x32_bf16(a0k2, C1, acc[0][1], 0, 0, 0); \
    acc[1][0] = __builtin_amdgcn_mfma_f32_16x16x32_bf16(a1k2, C0, acc[1][0], 0, 0, 0); \
    acc[1][1] = __builtin_amdgcn_mfma_f32_16x16x32_bf16(a1k2, C1, acc[1][1], 0, 0, 0); \
    const float bia0 = b1[32 * (C) + rfr];                                 \
    const float bia1 = b1[32 * (C) + 16 + rfr];                            \
    _Pragma("unroll")                                                      \
    for (int rt = 0; rt < 2; ++rt)                                         \
      _Pragma("unroll")                                                    \
      for (int reg = 0; reg < 4; ++reg) {                                  \
        const int row = 16 * rt + (lane >> 4) * 4 + reg;                   \
        Hs[row][32 * (C) + rfr]      = f2bf(fmaxf(acc[rt][0][reg] + bia0, 0.f)); \
        Hs[row][32 * (C) + 16 + rfr] = f2bf(fmaxf(acc[rt][1][reg] + bia1, 0.f)); \
      }                                                                    \
  } while (0)

  L1_CHUNK(0, wA0,wA1,wB0,wB1,wC0,wC1, xA0,xA1,xB0,xB1,xC0,xC1, true);
  L1_CHUNK(1, xA0,xA1,xB0,xB1,xC0,xC1, wA0,wA1,wB0,wB1,wC0,wC1, true);
  L1_CHUNK(2, wA0,wA1,wB0,wB1,wC0,wC1, xA0,xA1,xB0,xB1,xC0,xC1, true);
  L1_CHUNK(3, xA0,xA1,xB0,xB1,xC0,xC1, wA0,wA1,wB0,wB1,wC0,wC1, false);
#undef L1_CHUNK

  // same-wave LDS round-trip: ordered via lgkmcnt, no barrier needed
  short8v hf[8];
  #pragma unroll
  for (int ks = 0; ks < 4; ++ks) {
    hf[ks * 2 + 0] = *(const short8v*)&Hs[rfr][ks * 32 + koff];
    hf[ks * 2 + 1] = *(const short8v*)&Hs[16 + rfr][ks * 32 + koff];
  }

  // ---- Layer 2 + column max: rolling pair-prefetch across all 16 steps ----
  short8v p0 = LDW2(0, 0, 0), p1 = LDW2(0, 0, 1);  // (c=0, ks=0)
  short8v q0, q1;

#define L2_STEP(KS, CUR0, CUR1, NXT0, NXT1, NC, NKS, LAST)                 \
  do {                                                                     \
    if (!(LAST)) { NXT0 = LDW2(NKS, NC, 0); NXT1 = LDW2(NKS, NC, 1); }     \
    acc2[0][0] = __builtin_amdgcn_mfma_f32_16x16x32_bf16(hf[(KS) * 2 + 0], CUR0, acc2[0][0], 0, 0, 0); \
    acc2[0][1] = __builtin_amdgcn_mfma_f32_16x16x32_bf16(hf[(KS) * 2 + 0], CUR1, acc2[0][1], 0, 0, 0); \
    acc2[1][0] = __builtin_amdgcn_mfma_f32_16x16x32_bf16(hf[(KS) * 2 + 1], CUR0, acc2[1][0], 0, 0, 0); \
    acc2[1][1] = __builtin_amdgcn_mfma_f32_16x16x32_bf16(hf[(KS) * 2 + 1], CUR1, acc2[1][1], 0, 0, 0); \
  } while (0)

  #pragma unroll
  for (int c = 0; c < 4; ++c) {
    f32x4 acc2[2][2] = {};
    L2_STEP(0, p0, p1, q0, q1, c, 1, false);
    L2_STEP(1, q0, q1, p0, p1, c, 2, false);
    L2_STEP(2, p0, p1, q0, q1, c, 3, false);
    L2_STEP(3, q0, q1, p0, p1, c + 1, 0, c == 3);

    float m0 = -3.4e38f, m1 = -3.4e38f;
    #pragma unroll
    for (int rt = 0; rt < 2; ++rt)
      #pragma unroll
      for (int reg = 0; reg < 4; ++reg) {
        m0 = fmaxf(m0, acc2[rt][0][reg]);
        m1 = fmaxf(m1, acc2[rt][1][reg]);
      }
    m0 += b2[32 * c + rfr];
    m1 += b2[32 * c + 16 + rfr];
    m0 = fmaxf(m0, __shfl_xor(m0, 16));
    m0 = fmaxf(m0, __shfl_xor(m0, 32));
    m1 = fmaxf(m1, __shfl_xor(m1, 16));
    m1 = fmaxf(m1, __shfl_xor(m1, 32));
    if (lane < 16) {
      out[(size_t)bs * CPATCH + 32 * c + lane]      = m0;
      out[(size_t)bs * CPATCH + 32 * c + 16 + lane] = m1;
    }
  }
#undef L2_STEP
}

extern "C" void kernel_launch(void* const* d_in, const int* in_sizes, int n_in,
                              void* d_out, int out_size, void* d_ws, size_t ws_size,
                              hipStream_t stream) {
  const float* xyz = (const float*)d_in[0];
  const float* pf  = (const float*)d_in[1];
  const float* pc  = (const float*)d_in[2];
  const float* w1  = (const float*)d_in[3];
  const float* b1  = (const float*)d_in[4];
  const float* w2  = (const float*)d_in[5];
  const float* b2  = (const float*)d_in[6];

  float* out     = (float*)d_out;
  float* idx_out = out + (size_t)B_ * S_ * CPATCH;

  unsigned short* w1p = (unsigned short*)d_ws;          // 96*128 bf16
  unsigned short* w2p = w1p + 96 * 128;                 // 128*128 bf16

  pack_weights<<<14, 256, 0, stream>>>(w1, w2, w1p, w2p);
  fused_wave<<<B_ * S_, 64, 0, stream>>>(xyz, pf, pc, w1p, b1, w2p, b2,
                                         idx_out, out);
}